// Round 11
// baseline (331.745 us; speedup 1.0000x reference)
//
#include <hip/hip_runtime.h>
#include <hip/hip_bf16.h>
#include <math.h>

#define BETA 0.125f
#define INV_BETA 8.0f

typedef __attribute__((ext_vector_type(8))) short short8v;
typedef __attribute__((ext_vector_type(4))) float f32x4;
typedef union { short8v v; unsigned short u[8]; } v8u;

// ws layout (float units)
#define OFF_XB   0u          // bf16 x      [4096][1024]
#define OFF_WCB  2097152u    // bf16 Wcat   [2048][1024]
#define OFF_WCTB 3145728u    // bf16 WcatT  [1024][2048]
#define OFF_WHB  4194304u    // bf16 Whop   [1024][4096]
#define OFF_WHTB 6291456u    // bf16 WhopT  [4096][1024]
#define OFF_H    8388608u    // bf16 Hneg   [4096][4096]
#define OFF_QB   16777216u   // bf16 Qb     [64][1024][64]
#define OFF_KB   18874368u   // bf16 Kb
#define OFF_QT   20971520u   // bf16 QT     [64][64][1024]
#define OFF_KT   23068672u   // bf16 KT
#define OFF_DQK  25165824u   // bf16 dQKcat [4096][2048]
#define OFF_LSE  29360128u   // f32 [65536]
#define OFF_PL   29425664u   // f32 [4096]
#define OFF_PH   29429760u   // f32 [1024]

__device__ __forceinline__ unsigned short f2b(float f) {
    unsigned u = __float_as_uint(f);
    return (unsigned short)((u + 0x7fffu + ((u >> 16) & 1u)) >> 16);
}

__device__ __forceinline__ void gload_lds16(const unsigned short* g, void* l) {
    __builtin_amdgcn_global_load_lds(
        (const __attribute__((address_space(1))) unsigned int*)g,
        (__attribute__((address_space(3))) unsigned int*)l, 16, 0, 0);
}

// bijective XCD-chunked swizzle (bx fastest within an XCD chunk)
__device__ __forceinline__ void xcd_swz(int n, int gx, int& bx, int& by) {
    int id = blockIdx.x;
    int nid = (id & 7) * (n >> 3) + (id >> 3);
    bx = nid % gx;
    by = nid / gx;
}

// ---------------- fused prep: bf16 casts + bf16 transposes (one launch) ----------------
// blocks [0,10240): float4 casts of x/Wq/Wk/Whop
// blocks [10240,16384): transpose tiles (bx<64: WcatT, else WhopT)
__global__ __launch_bounds__(256) void k_prep(const float* __restrict__ x,
                                              const float* __restrict__ Wq,
                                              const float* __restrict__ Wk,
                                              const float* __restrict__ Whop,
                                              unsigned short* __restrict__ XB,
                                              unsigned short* __restrict__ WCB,
                                              unsigned short* __restrict__ WHB,
                                              unsigned short* __restrict__ WCTB,
                                              unsigned short* __restrict__ WHTB) {
    __shared__ float t[32][33];
    int id = blockIdx.x;
    int tid = threadIdx.x;
    if (id < 10240) {
        int i = id * 256 + tid;
        const float* s;
        unsigned short* d;
        int j;
        if (i < 1048576) { s = x; d = XB; j = i; }
        else if (i < 1310720) { s = Wq; d = WCB; j = i - 1048576; }
        else if (i < 1572864) { s = Wk; d = WCB + 1048576; j = i - 1310720; }
        else { s = Whop; d = WHB; j = i - 1572864; }
        float4 v = ((const float4*)s)[j];
        ushort4 o;
        o.x = f2b(v.x); o.y = f2b(v.y); o.z = f2b(v.z); o.w = f2b(v.w);
        ((ushort4*)d)[j] = o;
        return;
    }
    int id2 = id - 10240;
    int bx = id2 % 192;
    int byy = id2 / 192;
    int tx = tid & 31, ty = tid >> 5;
    if (bx < 64) {
        int j0 = bx * 32, d0 = byy * 32;
#pragma unroll
        for (int i = 0; i < 4; ++i) {
            int j = j0 + ty + 8 * i;
            const float* src = (j < 1024) ? (Wq + (size_t)j * 1024) : (Wk + (size_t)(j - 1024) * 1024);
            t[ty + 8 * i][tx] = src[d0 + tx];
        }
        __syncthreads();
#pragma unroll
        for (int i = 0; i < 4; ++i)
            WCTB[(size_t)(d0 + ty + 8 * i) * 2048 + j0 + tx] = f2b(t[tx][ty + 8 * i]);
    } else {
        int e0 = (bx - 64) * 32, d0 = byy * 32;
#pragma unroll
        for (int i = 0; i < 4; ++i)
            t[ty + 8 * i][tx] = Whop[(size_t)(d0 + ty + 8 * i) * 4096 + e0 + tx];
        __syncthreads();
#pragma unroll
        for (int i = 0; i < 4; ++i)
            WHTB[(size_t)(e0 + ty + 8 * i) * 1024 + d0 + tx] = f2b(t[tx][ty + 8 * i]);
    }
}

// ============ m97-structure single-buffer GEMM core (NT: A[M][K] x B[N][K]) ============
template <int MI, int NJ>
__device__ __forceinline__ void gemm_core(const unsigned short* __restrict__ A, int lda,
                                          const unsigned short* __restrict__ Bm, int ldb,
                                          int kdim, int rowBase, int colBase,
                                          unsigned short* ldsA, unsigned short* ldsB,
                                          f32x4 (&acc)[MI][NJ]) {
    const int tid = threadIdx.x, lane = tid & 63;
    const int wv = tid >> 6;
    const int lr = lane & 15, lg = lane >> 4;
    const int wrow = (wv >> 1) * (MI * 16);
    const int wcol = (wv & 1) * (NJ * 16);

    for (int kk = 0; kk < kdim; kk += 64) {
#pragma unroll
        for (int iss = 0; iss < MI; ++iss) {
            int p = iss * 256 + tid;
            int row = p >> 3, c = p & 7, cs = c ^ (row & 7);
            gload_lds16(&A[(size_t)(rowBase + row) * lda + kk + cs * 8], (char*)ldsA + p * 16);
        }
#pragma unroll
        for (int iss = 0; iss < NJ; ++iss) {
            int p = iss * 256 + tid;
            int row = p >> 3, c = p & 7, cs = c ^ (row & 7);
            gload_lds16(&Bm[(size_t)(colBase + row) * ldb + kk + cs * 8], (char*)ldsB + p * 16);
        }
        __syncthreads();
#pragma unroll
        for (int kc = 0; kc < 2; ++kc) {
            short8v av[MI], bv[NJ];
#pragma unroll
            for (int i = 0; i < MI; ++i) {
                int row = wrow + i * 16 + lr;
                av[i] = *(const short8v*)((const char*)ldsA + row * 128 + ((kc * 4 + lg) ^ (row & 7)) * 16);
            }
#pragma unroll
            for (int j = 0; j < NJ; ++j) {
                int row = wcol + j * 16 + lr;
                bv[j] = *(const short8v*)((const char*)ldsB + row * 128 + ((kc * 4 + lg) ^ (row & 7)) * 16);
            }
#pragma unroll
            for (int i = 0; i < MI; ++i)
#pragma unroll
                for (int j = 0; j < NJ; ++j)
                    acc[i][j] = __builtin_amdgcn_mfma_f32_16x16x32_bf16(av[i], bv[j], acc[i][j], 0, 0, 0);
        }
        __syncthreads();
    }
}

#define GEMM_IDX(MI, NJ, BX, BY)                                                 \
    const int tid = threadIdx.x, lane = tid & 63, wv = tid >> 6;                 \
    const int lr = lane & 15, lg = lane >> 4;                                    \
    const int row0 = (BX) * (MI * 32) + (wv >> 1) * (MI * 16);                   \
    const int col0 = (BY) * (NJ * 32) + (wv & 1) * (NJ * 16);                    \
    f32x4 acc[MI][NJ];                                                           \
    _Pragma("unroll") for (int i = 0; i < MI; ++i)                               \
        _Pragma("unroll") for (int j = 0; j < NJ; ++j)                           \
            acc[i][j] = (f32x4){0.f, 0.f, 0.f, 0.f};

// ---------------- K1: Q/K projection (BM=64, BN=128, grid 1024, swizzled) ----------------
__global__ __launch_bounds__(256) void mm_proj(const unsigned short* __restrict__ XB,
                                               const unsigned short* __restrict__ WCB,
                                               unsigned short* __restrict__ Qb,
                                               unsigned short* __restrict__ Kb) {
    __shared__ unsigned short ldsA[64 * 64];
    __shared__ unsigned short ldsB[128 * 64];
    int bx, by;
    xcd_swz(1024, 64, bx, by);
    GEMM_IDX(2, 4, bx, by)
    gemm_core<2, 4>(XB, 1024, WCB, 1024, 1024, bx * 64, by * 128, ldsA, ldsB, acc);
    unsigned short* dst = (col0 < 1024) ? Qb : Kb;
    const int cbase = col0 & 1023;
#pragma unroll
    for (int i = 0; i < 2; ++i)
#pragma unroll
        for (int r = 0; r < 4; ++r) {
            int rg = row0 + i * 16 + lg * 4 + r;
            int bb = rg >> 10, n = rg & 1023;
#pragma unroll
            for (int j = 0; j < 4; ++j) {
                int c = cbase + j * 16 + lr;
                int h = c >> 6, q = c & 63;
                dst[((size_t)(bb * 16 + h) * 1024 + n) * 64 + q] = f2b(acc[i][j][r]);
            }
        }
}

// ---------------- K6: Hneg = -relu(x Whop) (BM=128, BN=128, grid 1024, swizzled) ----------------
__global__ __launch_bounds__(256) void mm_hopfwd(const unsigned short* __restrict__ XB,
                                                 const unsigned short* __restrict__ WHTB,
                                                 unsigned short* __restrict__ Hn,
                                                 float* __restrict__ PH) {
    __shared__ unsigned short ldsA[128 * 64];
    __shared__ unsigned short ldsB[128 * 64];
    __shared__ float red[4];
    int bx, by;
    xcd_swz(1024, 32, bx, by);
    GEMM_IDX(4, 4, bx, by)
    gemm_core<4, 4>(XB, 1024, WHTB, 1024, 1024, bx * 128, by * 128, ldsA, ldsB, acc);
    float ss = 0.f;
#pragma unroll
    for (int i = 0; i < 4; ++i)
#pragma unroll
        for (int r = 0; r < 4; ++r) {
            size_t rg = row0 + i * 16 + lg * 4 + r;
#pragma unroll
            for (int j = 0; j < 4; ++j) {
                float hv = fmaxf(acc[i][j][r], 0.f);
                ss += hv * hv;
                Hn[rg * 4096 + col0 + j * 16 + lr] = f2b(-hv);
            }
        }
#pragma unroll
    for (int off = 32; off; off >>= 1) ss += __shfl_down(ss, off);
    if (lane == 0) red[wv] = ss;
    __syncthreads();
    if (tid == 0) PH[blockIdx.x] = red[0] + red[1] + red[2] + red[3];
}

// ---------------- K7+K5 fused: out = Hneg Whop^T + dQKcat WcatT ----------------
// BM=64, BN=128 -> grid 512; A-panel-clustered swizzle (by innermost within XCD chunk)
__global__ __launch_bounds__(256) void mm_gradall(const unsigned short* __restrict__ Hn,
                                                  const unsigned short* __restrict__ WHB,
                                                  const unsigned short* __restrict__ DQK,
                                                  const unsigned short* __restrict__ WCTB,
                                                  float* __restrict__ out) {
    __shared__ unsigned short ldsA[64 * 64];
    __shared__ unsigned short ldsB[128 * 64];
    int id = blockIdx.x;
    int nid = (id & 7) * 64 + (id >> 3);   // grid 512: 64 per XCD chunk
    int by = nid & 7;                      // by fastest -> same-bx (A-panel) blocks adjacent
    int bx = nid >> 3;
    GEMM_IDX(2, 4, bx, by)
    gemm_core<2, 4>(Hn, 4096, WHB, 4096, 4096, bx * 64, by * 128, ldsA, ldsB, acc);
    gemm_core<2, 4>(DQK, 2048, WCTB, 2048, 2048, bx * 64, by * 128, ldsA, ldsB, acc);
#pragma unroll
    for (int i = 0; i < 2; ++i)
#pragma unroll
        for (int r = 0; r < 4; ++r) {
            size_t rg = row0 + i * 16 + lg * 4 + r;
#pragma unroll
            for (int j = 0; j < 4; ++j)
                out[rg * 1024 + col0 + j * 16 + lr] = acc[i][j][r];
        }
}

// ---------------- transpose Qb/Kb -> QT/KT ----------------
__global__ __launch_bounds__(256) void k_tqk(const unsigned short* __restrict__ Qb,
                                             const unsigned short* __restrict__ Kb,
                                             unsigned short* __restrict__ QT,
                                             unsigned short* __restrict__ KT) {
    __shared__ unsigned short T[64][65];
    const int z = blockIdx.z;
    const unsigned short* src = z ? Kb : Qb;
    unsigned short* dst = z ? KT : QT;
    const int bh = blockIdx.y;
    const int n0 = blockIdx.x * 64;
    const int t = threadIdx.x;
    {
        int row = t >> 3;
        int colc = (t & 7) * 8;
#pragma unroll
        for (int ii = 0; ii < 2; ++ii) {
            int r = row + 32 * ii;
            v8u vv;
            vv.v = *(const short8v*)&src[((size_t)(bh << 10) + n0 + r) * 64 + colc];
#pragma unroll
            for (int j = 0; j < 8; ++j) T[r][colc + j] = vv.u[j];
        }
    }
    __syncthreads();
    {
        int q = t >> 2;
        int nc = (t & 3) * 16;
        unsigned short buf[16];
#pragma unroll
        for (int j = 0; j < 16; ++j) buf[j] = T[nc + j][q];
        *(short8v*)&dst[((size_t)bh * 64 + q) * 1024 + n0 + nc] = *(short8v*)&buf[0];
        *(short8v*)&dst[((size_t)bh * 64 + q) * 1024 + n0 + nc + 8] = *(short8v*)&buf[8];
    }
}

// ---------------- K3: fused lse + dQ (64 rows/block, grid 1024 1D swizzled) ----------------
__global__ __launch_bounds__(256) void k_dq(const unsigned short* __restrict__ Qb,
                                            const unsigned short* __restrict__ Kb,
                                            const unsigned short* __restrict__ KT,
                                            float* __restrict__ LSE,
                                            float* __restrict__ PL,
                                            unsigned short* __restrict__ DQK) {
    __shared__ unsigned short Ktile[2][64 * 64];
    __shared__ unsigned short Ttile[2][64 * 64];
    __shared__ unsigned short P[4][1024];
    int nt, bh;
    xcd_swz(1024, 16, nt, bh);  // same-bh blocks cluster per XCD
    const int tid = threadIdx.x, lane = tid & 63, wv = tid >> 6;
    const int nw = nt * 64 + wv * 16;
    const int lr = lane & 15, lg = lane >> 4;
    unsigned short* Pw = &P[wv][0];

    auto stage = [&](int buf, int m0) {
#pragma unroll
        for (int iss = 0; iss < 2; ++iss) {
            int p = iss * 256 + tid;
            int row = p >> 3, c = p & 7, cs = c ^ (row & 7);
            gload_lds16(&Kb[((size_t)(bh << 10) + m0 + row) * 64 + cs * 8],
                        (char*)&Ktile[buf][0] + p * 16);
            gload_lds16(&KT[((size_t)bh * 64 + row) * 1024 + m0 + cs * 8],
                        (char*)&Ttile[buf][0] + p * 16);
        }
    };

    short8v qa[2];
#pragma unroll
    for (int kc = 0; kc < 2; ++kc)
        qa[kc] = *(const short8v*)&Qb[((size_t)(bh << 10) + nw + lr) * 64 + kc * 32 + lg * 8];

    float sm[4];
    f32x4 dq[4];
#pragma unroll
    for (int r = 0; r < 4; ++r) sm[r] = 0.f;
#pragma unroll
    for (int qb = 0; qb < 4; ++qb) dq[qb] = (f32x4){0.f, 0.f, 0.f, 0.f};

    stage(0, 0);
    __syncthreads();
    int buf = 0;
    for (int mt = 0; mt < 16; ++mt) {
        if (mt < 15) stage(buf ^ 1, (mt + 1) * 64);
        const char* Kt = (const char*)&Ktile[buf][0];
        const char* Tt = (const char*)&Ttile[buf][0];
#pragma unroll
        for (int ct = 0; ct < 4; ++ct) {
            int brow = ct * 16 + lr;
            short8v bk0 = *(const short8v*)(Kt + brow * 128 + ((lg) ^ (brow & 7)) * 16);
            short8v bk1 = *(const short8v*)(Kt + brow * 128 + ((lg + 4) ^ (brow & 7)) * 16);
            f32x4 s = {0.f, 0.f, 0.f, 0.f};
            s = __builtin_amdgcn_mfma_f32_16x16x32_bf16(qa[0], bk0, s, 0, 0, 0);
            s = __builtin_amdgcn_mfma_f32_16x16x32_bf16(qa[1], bk1, s, 0, 0, 0);
#pragma unroll
            for (int r = 0; r < 4; ++r) {
                float p = __expf(s[r] * BETA);
                sm[r] += p;
                int row = lg * 4 + r;
                int off = (row * 64 + ct * 16 + lr) ^ ((row & 7) << 3);
                Pw[off] = f2b(p);
            }
        }
        short8v pa[2];
#pragma unroll
        for (int kc = 0; kc < 2; ++kc) {
            int off = (lr * 64 + kc * 32 + lg * 8) ^ ((lr & 7) << 3);
            pa[kc] = *(const short8v*)&Pw[off];
        }
#pragma unroll
        for (int qb = 0; qb < 4; ++qb) {
            int brow = qb * 16 + lr;
            short8v b0 = *(const short8v*)(Tt + brow * 128 + ((lg) ^ (brow & 7)) * 16);
            short8v b1 = *(const short8v*)(Tt + brow * 128 + ((lg + 4) ^ (brow & 7)) * 16);
            dq[qb] = __builtin_amdgcn_mfma_f32_16x16x32_bf16(pa[0], b0, dq[qb], 0, 0, 0);
            dq[qb] = __builtin_amdgcn_mfma_f32_16x16x32_bf16(pa[1], b1, dq[qb], 0, 0, 0);
        }
        __syncthreads();
        buf ^= 1;
    }

#pragma unroll
    for (int off = 1; off < 16; off <<= 1)
#pragma unroll
        for (int r = 0; r < 4; ++r) sm[r] += __shfl_xor(sm[r], off);

    const int b = bh >> 4, h = bh & 15;
#pragma unroll
    for (int r = 0; r < 4; ++r) {
        float inv = 1.0f / sm[r];
#pragma unroll
        for (int qb = 0; qb < 4; ++qb)
            DQK[((size_t)(b << 10) + nw + lg * 4 + r) * 2048 + h * 64 + qb * 16 + lr] =
                f2b(-dq[qb][r] * inv);
    }

    float lsum = 0.f;
    if (lr == 0) {
#pragma unroll
        for (int r = 0; r < 4; ++r) {
            float l = __logf(sm[r]);
            LSE[(size_t)(bh << 10) + nw + lg * 4 + r] = l;
            lsum += l;
        }
    }
    lsum += __shfl_xor(lsum, 16);
    lsum += __shfl_xor(lsum, 32);
    if (lane == 0) PL[(size_t)blockIdx.x * 4 + wv] = lsum;
}

// ---------------- K4: dK = -P^T Q (64 rows/block, grid 1024 1D swizzled) ----------------
__global__ __launch_bounds__(256) void k_dk(const unsigned short* __restrict__ Qb,
                                            const unsigned short* __restrict__ Kb,
                                            const unsigned short* __restrict__ QT,
                                            const float* __restrict__ LSE,
                                            unsigned short* __restrict__ DQK) {
    __shared__ unsigned short Qtile[2][64 * 64];
    __shared__ unsigned short Ttile[2][64 * 64];
    __shared__ unsigned short P[4][1024];
    int mt, bh;
    xcd_swz(1024, 16, mt, bh);
    const int tid = threadIdx.x, lane = tid & 63, wv = tid >> 6;
    const int mw = mt * 64 + wv * 16;
    const int lr = lane & 15, lg = lane >> 4;
    unsigned short* Pw = &P[wv][0];

    auto stage = [&](int buf, int n0) {
#pragma unroll
        for (int iss = 0; iss < 2; ++iss) {
            int p = iss * 256 + tid;
            int row = p >> 3, c = p & 7, cs = c ^ (row & 7);
            gload_lds16(&Qb[((size_t)(bh << 10) + n0 + row) * 64 + cs * 8],
                        (char*)&Qtile[buf][0] + p * 16);
            gload_lds16(&QT[((size_t)bh * 64 + row) * 1024 + n0 + cs * 8],
                        (char*)&Ttile[buf][0] + p * 16);
        }
    };

    short8v ka[2];
#pragma unroll
    for (int kc = 0; kc < 2; ++kc)
        ka[kc] = *(const short8v*)&Kb[((size_t)(bh << 10) + mw + lr) * 64 + kc * 32 + lg * 8];

    f32x4 dk[4];
#pragma unroll
    for (int qb = 0; qb < 4; ++qb) dk[qb] = (f32x4){0.f, 0.f, 0.f, 0.f};

    stage(0, 0);
    __syncthreads();
    int buf = 0;
    for (int ntl = 0; ntl < 16; ++ntl) {
        const int n0 = ntl * 64;
        float lse_c[4];
#pragma unroll
        for (int ct = 0; ct < 4; ++ct)
            lse_c[ct] = LSE[(size_t)(bh << 10) + n0 + ct * 16 + lr];
        if (ntl < 15) stage(buf ^ 1, n0 + 64);
        const char* Qt = (const char*)&Qtile[buf][0];
        const char* Tt = (const char*)&Ttile[buf][0];
#pragma unroll
        for (int ct = 0; ct < 4; ++ct) {
            int brow = ct * 16 + lr;
            short8v bq0 = *(const short8v*)(Qt + brow * 128 + ((lg) ^ (brow & 7)) * 16);
            short8v bq1 = *(const short8v*)(Qt + brow * 128 + ((lg + 4) ^ (brow & 7)) * 16);
            f32x4 s = {0.f, 0.f, 0.f, 0.f};
            s = __builtin_amdgcn_mfma_f32_16x16x32_bf16(ka[0], bq0, s, 0, 0, 0);
            s = __builtin_amdgcn_mfma_f32_16x16x32_bf16(ka[1], bq1, s, 0, 0, 0);
#pragma unroll
            for (int r = 0; r < 4; ++r) {
                float p = __expf(s[r] * BETA - lse_c[ct]);
                int row = lg * 4 + r;
                int off = (row * 64 + ct * 16 + lr) ^ ((row & 7) << 3);
                Pw[off] = f2b(p);
            }
        }
        short8v pa[2];
#pragma unroll
        for (int kc = 0; kc < 2; ++kc) {
            int off = (lr * 64 + kc * 32 + lg * 8) ^ ((lr & 7) << 3);
            pa[kc] = *(const short8v*)&Pw[off];
        }
#pragma unroll
        for (int qb = 0; qb < 4; ++qb) {
            int brow = qb * 16 + lr;
            short8v b0 = *(const short8v*)(Tt + brow * 128 + ((lg) ^ (brow & 7)) * 16);
            short8v b1 = *(const short8v*)(Tt + brow * 128 + ((lg + 4) ^ (brow & 7)) * 16);
            dk[qb] = __builtin_amdgcn_mfma_f32_16x16x32_bf16(pa[0], b0, dk[qb], 0, 0, 0);
            dk[qb] = __builtin_amdgcn_mfma_f32_16x16x32_bf16(pa[1], b1, dk[qb], 0, 0, 0);
        }
        __syncthreads();
        buf ^= 1;
    }
    const int b = bh >> 4, h = bh & 15;
#pragma unroll
    for (int qb = 0; qb < 4; ++qb)
#pragma unroll
        for (int r = 0; r < 4; ++r)
            DQK[((size_t)(b << 10) + mw + lg * 4 + r) * 2048 + 1024 + h * 64 + qb * 16 + lr] = f2b(-dk[qb][r]);
}

// ---------------- K8: finalize energy ----------------
__global__ __launch_bounds__(256) void k_fin(const float* __restrict__ pl,
                                             const float* __restrict__ ph,
                                             float* __restrict__ out) {
    const int tid = threadIdx.x;
    float s1 = 0.f, s2 = 0.f;
    for (int i = tid; i < 4096; i += 256) s1 += pl[i];
    for (int i = tid; i < 1024; i += 256) s2 += ph[i];
#pragma unroll
    for (int off = 32; off; off >>= 1) {
        s1 += __shfl_down(s1, off);
        s2 += __shfl_down(s2, off);
    }
    __shared__ float r1[4], r2[4];
    if ((tid & 63) == 0) { r1[tid >> 6] = s1; r2[tid >> 6] = s2; }
    __syncthreads();
    if (tid == 0) {
        float S1 = r1[0] + r1[1] + r1[2] + r1[3];
        float S2 = r2[0] + r2[1] + r2[2] + r2[3];
        out[(size_t)4194304] = -INV_BETA * S1 - 0.5f * S2;
    }
}

extern "C" void kernel_launch(void* const* d_in, const int* in_sizes, int n_in,
                              void* d_out, int out_size, void* d_ws, size_t ws_size,
                              hipStream_t stream) {
    (void)in_sizes; (void)n_in; (void)out_size; (void)ws_size;
    const float* x    = (const float*)d_in[0];
    const float* Wq   = (const float*)d_in[1];
    const float* Wk   = (const float*)d_in[2];
    const float* Whop = (const float*)d_in[3];
    float* out = (float*)d_out;
    float* ws = (float*)d_ws;

    unsigned short* XB   = (unsigned short*)(ws + OFF_XB);
    unsigned short* WCB  = (unsigned short*)(ws + OFF_WCB);
    unsigned short* WCTB = (unsigned short*)(ws + OFF_WCTB);
    unsigned short* WHB  = (unsigned short*)(ws + OFF_WHB);
    unsigned short* WHTB = (unsigned short*)(ws + OFF_WHTB);
    unsigned short* Hn   = (unsigned short*)(ws + OFF_H);
    unsigned short* Qb   = (unsigned short*)(ws + OFF_QB);
    unsigned short* Kb   = (unsigned short*)(ws + OFF_KB);
    unsigned short* QT   = (unsigned short*)(ws + OFF_QT);
    unsigned short* KT   = (unsigned short*)(ws + OFF_KT);
    unsigned short* DQK  = (unsigned short*)(ws + OFF_DQK);
    float* LSE = ws + OFF_LSE;
    float* PL  = ws + OFF_PL;
    float* PH  = ws + OFF_PH;

    dim3 blk(256);
    k_prep<<<dim3(16384), blk, 0, stream>>>(x, Wq, Wk, Whop, XB, WCB, WHB, WCTB, WHTB);

    mm_proj<<<dim3(1024), blk, 0, stream>>>(XB, WCB, Qb, Kb);
    k_tqk<<<dim3(16, 64, 2), blk, 0, stream>>>(Qb, Kb, QT, KT);
    k_dq<<<dim3(1024), blk, 0, stream>>>(Qb, Kb, KT, LSE, PL, DQK);
    k_dk<<<dim3(1024), blk, 0, stream>>>(Qb, Kb, QT, LSE, DQK);

    mm_hopfwd<<<dim3(1024), blk, 0, stream>>>(XB, WHTB, Hn, PH);
    mm_gradall<<<dim3(512), blk, 0, stream>>>(Hn, WHB, DQK, WCTB, out);
    k_fin<<<dim3(1), blk, 0, stream>>>(PL, PH, out);
}

// Round 12
// 325.565 us; speedup vs baseline: 1.0190x; 1.0190x over previous
//
#include <hip/hip_runtime.h>
#include <hip/hip_bf16.h>
#include <math.h>

#define BETA 0.125f
#define INV_BETA 8.0f

typedef __attribute__((ext_vector_type(8))) short short8v;
typedef __attribute__((ext_vector_type(4))) float f32x4;
typedef union { short8v v; unsigned short u[8]; } v8u;

// ws layout (float units)
#define OFF_XB   0u          // bf16 x      [4096][1024]
#define OFF_WCB  2097152u    // bf16 Wcat   [2048][1024]
#define OFF_WCTB 3145728u    // bf16 WcatT  [1024][2048]
#define OFF_WHB  4194304u    // bf16 Whop   [1024][4096]
#define OFF_WHTB 6291456u    // bf16 WhopT  [4096][1024]
#define OFF_H    8388608u    // bf16 Hneg   [4096][4096]
#define OFF_QB   16777216u   // bf16 Qb     [64][1024][64]
#define OFF_KB   18874368u   // bf16 Kb
#define OFF_QT   20971520u   // bf16 QT     [64][64][1024]
#define OFF_KT   23068672u   // bf16 KT
#define OFF_DQK  25165824u   // bf16 dQKcat [4096][2048]
#define OFF_LSE  29360128u   // f32 [65536]
#define OFF_PL   29425664u   // f32 [4096]
#define OFF_PH   29429760u   // f32 [256]

__device__ __forceinline__ unsigned short f2b(float f) {
    unsigned u = __float_as_uint(f);
    return (unsigned short)((u + 0x7fffu + ((u >> 16) & 1u)) >> 16);
}

__device__ __forceinline__ void gload_lds16(const unsigned short* g, void* l) {
    __builtin_amdgcn_global_load_lds(
        (const __attribute__((address_space(1))) unsigned int*)g,
        (__attribute__((address_space(3))) unsigned int*)l, 16, 0, 0);
}

// bijective XCD-chunked swizzle (bx fastest within an XCD chunk)
__device__ __forceinline__ void xcd_swz(int n, int gx, int& bx, int& by) {
    int id = blockIdx.x;
    int nid = (id & 7) * (n >> 3) + (id >> 3);
    bx = nid % gx;
    by = nid / gx;
}

// ---------------- fused prep: bf16 casts + bf16 transposes (one launch) ----------------
__global__ __launch_bounds__(256) void k_prep(const float* __restrict__ x,
                                              const float* __restrict__ Wq,
                                              const float* __restrict__ Wk,
                                              const float* __restrict__ Whop,
                                              unsigned short* __restrict__ XB,
                                              unsigned short* __restrict__ WCB,
                                              unsigned short* __restrict__ WHB,
                                              unsigned short* __restrict__ WCTB,
                                              unsigned short* __restrict__ WHTB) {
    __shared__ float t[32][33];
    int id = blockIdx.x;
    int tid = threadIdx.x;
    if (id < 10240) {
        int i = id * 256 + tid;
        const float* s;
        unsigned short* d;
        int j;
        if (i < 1048576) { s = x; d = XB; j = i; }
        else if (i < 1310720) { s = Wq; d = WCB; j = i - 1048576; }
        else if (i < 1572864) { s = Wk; d = WCB + 1048576; j = i - 1310720; }
        else { s = Whop; d = WHB; j = i - 1572864; }
        float4 v = ((const float4*)s)[j];
        ushort4 o;
        o.x = f2b(v.x); o.y = f2b(v.y); o.z = f2b(v.z); o.w = f2b(v.w);
        ((ushort4*)d)[j] = o;
        return;
    }
    int id2 = id - 10240;
    int bx = id2 % 192;
    int byy = id2 / 192;
    int tx = tid & 31, ty = tid >> 5;
    if (bx < 64) {
        int j0 = bx * 32, d0 = byy * 32;
#pragma unroll
        for (int i = 0; i < 4; ++i) {
            int j = j0 + ty + 8 * i;
            const float* src = (j < 1024) ? (Wq + (size_t)j * 1024) : (Wk + (size_t)(j - 1024) * 1024);
            t[ty + 8 * i][tx] = src[d0 + tx];
        }
        __syncthreads();
#pragma unroll
        for (int i = 0; i < 4; ++i)
            WCTB[(size_t)(d0 + ty + 8 * i) * 2048 + j0 + tx] = f2b(t[tx][ty + 8 * i]);
    } else {
        int e0 = (bx - 64) * 32, d0 = byy * 32;
#pragma unroll
        for (int i = 0; i < 4; ++i)
            t[ty + 8 * i][tx] = Whop[(size_t)(d0 + ty + 8 * i) * 4096 + e0 + tx];
        __syncthreads();
#pragma unroll
        for (int i = 0; i < 4; ++i)
            WHTB[(size_t)(e0 + ty + 8 * i) * 1024 + d0 + tx] = f2b(t[tx][ty + 8 * i]);
    }
}

// ============ m97-structure single-buffer GEMM core (NT: A[M][K] x B[N][K]) ============
template <int MI, int NJ>
__device__ __forceinline__ void gemm_core(const unsigned short* __restrict__ A, int lda,
                                          const unsigned short* __restrict__ Bm, int ldb,
                                          int kdim, int rowBase, int colBase,
                                          unsigned short* ldsA, unsigned short* ldsB,
                                          f32x4 (&acc)[MI][NJ]) {
    const int tid = threadIdx.x, lane = tid & 63;
    const int wv = tid >> 6;
    const int lr = lane & 15, lg = lane >> 4;
    const int wrow = (wv >> 1) * (MI * 16);
    const int wcol = (wv & 1) * (NJ * 16);

    for (int kk = 0; kk < kdim; kk += 64) {
#pragma unroll
        for (int iss = 0; iss < MI; ++iss) {
            int p = iss * 256 + tid;
            int row = p >> 3, c = p & 7, cs = c ^ (row & 7);
            gload_lds16(&A[(size_t)(rowBase + row) * lda + kk + cs * 8], (char*)ldsA + p * 16);
        }
#pragma unroll
        for (int iss = 0; iss < NJ; ++iss) {
            int p = iss * 256 + tid;
            int row = p >> 3, c = p & 7, cs = c ^ (row & 7);
            gload_lds16(&Bm[(size_t)(colBase + row) * ldb + kk + cs * 8], (char*)ldsB + p * 16);
        }
        __syncthreads();
#pragma unroll
        for (int kc = 0; kc < 2; ++kc) {
            short8v av[MI], bv[NJ];
#pragma unroll
            for (int i = 0; i < MI; ++i) {
                int row = wrow + i * 16 + lr;
                av[i] = *(const short8v*)((const char*)ldsA + row * 128 + ((kc * 4 + lg) ^ (row & 7)) * 16);
            }
#pragma unroll
            for (int j = 0; j < NJ; ++j) {
                int row = wcol + j * 16 + lr;
                bv[j] = *(const short8v*)((const char*)ldsB + row * 128 + ((kc * 4 + lg) ^ (row & 7)) * 16);
            }
#pragma unroll
            for (int i = 0; i < MI; ++i)
#pragma unroll
                for (int j = 0; j < NJ; ++j)
                    acc[i][j] = __builtin_amdgcn_mfma_f32_16x16x32_bf16(av[i], bv[j], acc[i][j], 0, 0, 0);
        }
        __syncthreads();
    }
}

#define GEMM_IDX(MI, NJ, BX, BY)                                                 \
    const int tid = threadIdx.x, lane = tid & 63, wv = tid >> 6;                 \
    const int lr = lane & 15, lg = lane >> 4;                                    \
    const int row0 = (BX) * (MI * 32) + (wv >> 1) * (MI * 16);                   \
    const int col0 = (BY) * (NJ * 32) + (wv & 1) * (NJ * 16);                    \
    f32x4 acc[MI][NJ];                                                           \
    _Pragma("unroll") for (int i = 0; i < MI; ++i)                               \
        _Pragma("unroll") for (int j = 0; j < NJ; ++j)                           \
            acc[i][j] = (f32x4){0.f, 0.f, 0.f, 0.f};

// ---------------- K1: Q/K projection (BM=64, BN=128, grid 1024, swizzled) ----------------
__global__ __launch_bounds__(256) void mm_proj(const unsigned short* __restrict__ XB,
                                               const unsigned short* __restrict__ WCB,
                                               unsigned short* __restrict__ Qb,
                                               unsigned short* __restrict__ Kb) {
    __shared__ unsigned short ldsA[64 * 64];
    __shared__ unsigned short ldsB[128 * 64];
    int bx, by;
    xcd_swz(1024, 64, bx, by);
    GEMM_IDX(2, 4, bx, by)
    gemm_core<2, 4>(XB, 1024, WCB, 1024, 1024, bx * 64, by * 128, ldsA, ldsB, acc);
    unsigned short* dst = (col0 < 1024) ? Qb : Kb;
    const int cbase = col0 & 1023;
#pragma unroll
    for (int i = 0; i < 2; ++i)
#pragma unroll
        for (int r = 0; r < 4; ++r) {
            int rg = row0 + i * 16 + lg * 4 + r;
            int bb = rg >> 10, n = rg & 1023;
#pragma unroll
            for (int j = 0; j < 4; ++j) {
                int c = cbase + j * 16 + lr;
                int h = c >> 6, q = c & 63;
                dst[((size_t)(bb * 16 + h) * 1024 + n) * 64 + q] = f2b(acc[i][j][r]);
            }
        }
}

// ---------------- K6: Hneg = -relu(x Whop) — 256^2 8-phase template ----------------
// 512 threads, 8 waves (2M x 4N), wave tile 128x64, BK=64, 128KB LDS double-buffer.
// Per K-step: 4 phases {stage 1 half-tile of step t+1; (phase0: vmcnt(2)); barrier;
//   12 ds_read_b128; setprio(1); 16 MFMA; setprio(0); barrier}. Never vmcnt(0) in loop.
__global__ __launch_bounds__(512) void mm_hopfwd(const unsigned short* __restrict__ XB,
                                                 const unsigned short* __restrict__ WHTB,
                                                 unsigned short* __restrict__ Hn,
                                                 float* __restrict__ PH) {
    __shared__ unsigned short ldsA[2][256 * 64];
    __shared__ unsigned short ldsB[2][256 * 64];
    __shared__ float red[8];
    const int tid = threadIdx.x, lane = tid & 63, wv = tid >> 6;
    const int lr = lane & 15, lg = lane >> 4;
    const int wm = wv >> 2, wn = wv & 3;
    int id = blockIdx.x;
    int nid = (id & 7) * 32 + (id >> 3);   // XCD swizzle, grid 256
    int bx = nid & 15, by = nid >> 4;
    const int rowB = bx * 256, colB = by * 256;

    f32x4 acc[8][4];
#pragma unroll
    for (int i = 0; i < 8; ++i)
#pragma unroll
        for (int j = 0; j < 4; ++j) acc[i][j] = (f32x4){0.f, 0.f, 0.f, 0.f};

    auto stageh = [&](int h, int tstep, int bufi) {
        const bool isB = (h & 1) != 0;          // order: A0,B0,A1,B1
        const int half = h >> 1;
        const unsigned short* gsrc = isB ? WHTB : XB;
        const int gbase = (isB ? colB : rowB) + half * 128;
        char* ldst = (char*)(isB ? &ldsB[bufi][0] : &ldsA[bufi][0]) + half * 16384;
        const int kk = tstep * 64;
#pragma unroll
        for (int iss = 0; iss < 2; ++iss) {
            int p = iss * 512 + tid;
            int row = p >> 3, c = p & 7, cs = c ^ (row & 7);
            gload_lds16(&gsrc[(size_t)(gbase + row) * 1024 + kk + cs * 8], ldst + p * 16);
        }
    };

    // prologue: fully stage K-step 0 into buffer 0 (one-time drain)
    stageh(0, 0, 0); stageh(1, 0, 0); stageh(2, 0, 0); stageh(3, 0, 0);
    asm volatile("s_waitcnt vmcnt(0)" ::: "memory");
    asm volatile("s_barrier" ::: "memory");

    for (int t = 0; t < 16; ++t) {
        const int cur = t & 1;
        const char* bufA = (const char*)&ldsA[cur][0] + wm * 16384;
        const char* bufB = (const char*)&ldsB[cur][0] + (wn >> 1) * 16384;
        const int bloc = (wn & 1) * 64;
#pragma unroll
        for (int q = 0; q < 4; ++q) {
            const int qm = q >> 1, qn = q & 1;
            if (t + 1 < 16) stageh(q, t + 1, cur ^ 1);
            if (q == 0) asm volatile("s_waitcnt vmcnt(2)" ::: "memory");
            asm volatile("s_barrier" ::: "memory");
            short8v av[4][2], bv[2][2];
#pragma unroll
            for (int m2 = 0; m2 < 4; ++m2) {
                int lrow = (qm * 4 + m2) * 16 + lr;
#pragma unroll
                for (int kc = 0; kc < 2; ++kc)
                    av[m2][kc] = *(const short8v*)(bufA + lrow * 128 + (((kc * 4 + lg) ^ (lrow & 7)) * 16));
            }
#pragma unroll
            for (int n2 = 0; n2 < 2; ++n2) {
                int lrow = bloc + (qn * 2 + n2) * 16 + lr;
#pragma unroll
                for (int kc = 0; kc < 2; ++kc)
                    bv[n2][kc] = *(const short8v*)(bufB + lrow * 128 + (((kc * 4 + lg) ^ (lrow & 7)) * 16));
            }
            __builtin_amdgcn_s_setprio(1);
#pragma unroll
            for (int m2 = 0; m2 < 4; ++m2)
#pragma unroll
                for (int n2 = 0; n2 < 2; ++n2)
#pragma unroll
                    for (int kc = 0; kc < 2; ++kc)
                        acc[qm * 4 + m2][qn * 2 + n2] = __builtin_amdgcn_mfma_f32_16x16x32_bf16(
                            av[m2][kc], bv[n2][kc], acc[qm * 4 + m2][qn * 2 + n2], 0, 0, 0);
            __builtin_amdgcn_s_setprio(0);
            asm volatile("s_barrier" ::: "memory");
        }
    }

    // epilogue: relu, square-sum, store -relu(H)
    float ss = 0.f;
#pragma unroll
    for (int mf = 0; mf < 8; ++mf)
#pragma unroll
        for (int r = 0; r < 4; ++r) {
            size_t rg = rowB + wm * 128 + mf * 16 + lg * 4 + r;
#pragma unroll
            for (int nf = 0; nf < 4; ++nf) {
                float hv = fmaxf(acc[mf][nf][r], 0.f);
                ss += hv * hv;
                Hn[rg * 4096 + colB + wn * 64 + nf * 16 + lr] = f2b(-hv);
            }
        }
#pragma unroll
    for (int off = 32; off; off >>= 1) ss += __shfl_down(ss, off);
    if (lane == 0) red[wv] = ss;
    __syncthreads();
    if (tid == 0) {
        float s = 0.f;
#pragma unroll
        for (int w = 0; w < 8; ++w) s += red[w];
        PH[blockIdx.x] = s;
    }
}

// ---------------- K7+K5 fused: out = Hneg Whop^T + dQKcat WcatT ----------------
__global__ __launch_bounds__(256) void mm_gradall(const unsigned short* __restrict__ Hn,
                                                  const unsigned short* __restrict__ WHB,
                                                  const unsigned short* __restrict__ DQK,
                                                  const unsigned short* __restrict__ WCTB,
                                                  float* __restrict__ out) {
    __shared__ unsigned short ldsA[64 * 64];
    __shared__ unsigned short ldsB[128 * 64];
    int id = blockIdx.x;
    int nid = (id & 7) * 64 + (id >> 3);
    int by = nid & 7;
    int bx = nid >> 3;
    GEMM_IDX(2, 4, bx, by)
    gemm_core<2, 4>(Hn, 4096, WHB, 4096, 4096, bx * 64, by * 128, ldsA, ldsB, acc);
    gemm_core<2, 4>(DQK, 2048, WCTB, 2048, 2048, bx * 64, by * 128, ldsA, ldsB, acc);
#pragma unroll
    for (int i = 0; i < 2; ++i)
#pragma unroll
        for (int r = 0; r < 4; ++r) {
            size_t rg = row0 + i * 16 + lg * 4 + r;
#pragma unroll
            for (int j = 0; j < 4; ++j)
                out[rg * 1024 + col0 + j * 16 + lr] = acc[i][j][r];
        }
}

// ---------------- transpose Qb/Kb -> QT/KT ----------------
__global__ __launch_bounds__(256) void k_tqk(const unsigned short* __restrict__ Qb,
                                             const unsigned short* __restrict__ Kb,
                                             unsigned short* __restrict__ QT,
                                             unsigned short* __restrict__ KT) {
    __shared__ unsigned short T[64][65];
    const int z = blockIdx.z;
    const unsigned short* src = z ? Kb : Qb;
    unsigned short* dst = z ? KT : QT;
    const int bh = blockIdx.y;
    const int n0 = blockIdx.x * 64;
    const int t = threadIdx.x;
    {
        int row = t >> 3;
        int colc = (t & 7) * 8;
#pragma unroll
        for (int ii = 0; ii < 2; ++ii) {
            int r = row + 32 * ii;
            v8u vv;
            vv.v = *(const short8v*)&src[((size_t)(bh << 10) + n0 + r) * 64 + colc];
#pragma unroll
            for (int j = 0; j < 8; ++j) T[r][colc + j] = vv.u[j];
        }
    }
    __syncthreads();
    {
        int q = t >> 2;
        int nc = (t & 3) * 16;
        unsigned short buf[16];
#pragma unroll
        for (int j = 0; j < 16; ++j) buf[j] = T[nc + j][q];
        *(short8v*)&dst[((size_t)bh * 64 + q) * 1024 + n0 + nc] = *(short8v*)&buf[0];
        *(short8v*)&dst[((size_t)bh * 64 + q) * 1024 + n0 + nc + 8] = *(short8v*)&buf[8];
    }
}

// ---------------- K3: fused lse + dQ (64 rows/block, grid 1024 1D swizzled) ----------------
__global__ __launch_bounds__(256) void k_dq(const unsigned short* __restrict__ Qb,
                                            const unsigned short* __restrict__ Kb,
                                            const unsigned short* __restrict__ KT,
                                            float* __restrict__ LSE,
                                            float* __restrict__ PL,
                                            unsigned short* __restrict__ DQK) {
    __shared__ unsigned short Ktile[2][64 * 64];
    __shared__ unsigned short Ttile[2][64 * 64];
    __shared__ unsigned short P[4][1024];
    int nt, bh;
    xcd_swz(1024, 16, nt, bh);
    const int tid = threadIdx.x, lane = tid & 63, wv = tid >> 6;
    const int nw = nt * 64 + wv * 16;
    const int lr = lane & 15, lg = lane >> 4;
    unsigned short* Pw = &P[wv][0];

    auto stage = [&](int buf, int m0) {
#pragma unroll
        for (int iss = 0; iss < 2; ++iss) {
            int p = iss * 256 + tid;
            int row = p >> 3, c = p & 7, cs = c ^ (row & 7);
            gload_lds16(&Kb[((size_t)(bh << 10) + m0 + row) * 64 + cs * 8],
                        (char*)&Ktile[buf][0] + p * 16);
            gload_lds16(&KT[((size_t)bh * 64 + row) * 1024 + m0 + cs * 8],
                        (char*)&Ttile[buf][0] + p * 16);
        }
    };

    short8v qa[2];
#pragma unroll
    for (int kc = 0; kc < 2; ++kc)
        qa[kc] = *(const short8v*)&Qb[((size_t)(bh << 10) + nw + lr) * 64 + kc * 32 + lg * 8];

    float sm[4];
    f32x4 dq[4];
#pragma unroll
    for (int r = 0; r < 4; ++r) sm[r] = 0.f;
#pragma unroll
    for (int qb = 0; qb < 4; ++qb) dq[qb] = (f32x4){0.f, 0.f, 0.f, 0.f};

    stage(0, 0);
    __syncthreads();
    int buf = 0;
    for (int mt = 0; mt < 16; ++mt) {
        if (mt < 15) stage(buf ^ 1, (mt + 1) * 64);
        const char* Kt = (const char*)&Ktile[buf][0];
        const char* Tt = (const char*)&Ttile[buf][0];
#pragma unroll
        for (int ct = 0; ct < 4; ++ct) {
            int brow = ct * 16 + lr;
            short8v bk0 = *(const short8v*)(Kt + brow * 128 + ((lg) ^ (brow & 7)) * 16);
            short8v bk1 = *(const short8v*)(Kt + brow * 128 + ((lg + 4) ^ (brow & 7)) * 16);
            f32x4 s = {0.f, 0.f, 0.f, 0.f};
            s = __builtin_amdgcn_mfma_f32_16x16x32_bf16(qa[0], bk0, s, 0, 0, 0);
            s = __builtin_amdgcn_mfma_f32_16x16x32_bf16(qa[1], bk1, s, 0, 0, 0);
#pragma unroll
            for (int r = 0; r < 4; ++r) {
                float p = __expf(s[r] * BETA);
                sm[r] += p;
                int row = lg * 4 + r;
                int off = (row * 64 + ct * 16 + lr) ^ ((row & 7) << 3);
                Pw[off] = f2b(p);
            }
        }
        short8v pa[2];
#pragma unroll
        for (int kc = 0; kc < 2; ++kc) {
            int off = (lr * 64 + kc * 32 + lg * 8) ^ ((lr & 7) << 3);
            pa[kc] = *(const short8v*)&Pw[off];
        }
#pragma unroll
        for (int qb = 0; qb < 4; ++qb) {
            int brow = qb * 16 + lr;
            short8v b0 = *(const short8v*)(Tt + brow * 128 + ((lg) ^ (brow & 7)) * 16);
            short8v b1 = *(const short8v*)(Tt + brow * 128 + ((lg + 4) ^ (brow & 7)) * 16);
            dq[qb] = __builtin_amdgcn_mfma_f32_16x16x32_bf16(pa[0], b0, dq[qb], 0, 0, 0);
            dq[qb] = __builtin_amdgcn_mfma_f32_16x16x32_bf16(pa[1], b1, dq[qb], 0, 0, 0);
        }
        __syncthreads();
        buf ^= 1;
    }

#pragma unroll
    for (int off = 1; off < 16; off <<= 1)
#pragma unroll
        for (int r = 0; r < 4; ++r) sm[r] += __shfl_xor(sm[r], off);

    const int b = bh >> 4, h = bh & 15;
#pragma unroll
    for (int r = 0; r < 4; ++r) {
        float inv = 1.0f / sm[r];
#pragma unroll
        for (int qb = 0; qb < 4; ++qb)
            DQK[((size_t)(b << 10) + nw + lg * 4 + r) * 2048 + h * 64 + qb * 16 + lr] =
                f2b(-dq[qb][r] * inv);
    }

    float lsum = 0.f;
    if (lr == 0) {
#pragma unroll
        for (int r = 0; r < 4; ++r) {
            float l = __logf(sm[r]);
            LSE[(size_t)(bh << 10) + nw + lg * 4 + r] = l;
            lsum += l;
        }
    }
    lsum += __shfl_xor(lsum, 16);
    lsum += __shfl_xor(lsum, 32);
    if (lane == 0) PL[(size_t)blockIdx.x * 4 + wv] = lsum;
}

// ---------------- K4: dK = -P^T Q (64 rows/block, grid 1024 1D swizzled) ----------------
__global__ __launch_bounds__(256) void k_dk(const unsigned short* __restrict__ Qb,
                                            const unsigned short* __restrict__ Kb,
                                            const unsigned short* __restrict__ QT,
                                            const float* __restrict__ LSE,
                                            unsigned short* __restrict__ DQK) {
    __shared__ unsigned short Qtile[2][64 * 64];
    __shared__ unsigned short Ttile[2][64 * 64];
    __shared__ unsigned short P[4][1024];
    int mt, bh;
    xcd_swz(1024, 16, mt, bh);
    const int tid = threadIdx.x, lane = tid & 63, wv = tid >> 6;
    const int mw = mt * 64 + wv * 16;
    const int lr = lane & 15, lg = lane >> 4;
    unsigned short* Pw = &P[wv][0];

    auto stage = [&](int buf, int n0) {
#pragma unroll
        for (int iss = 0; iss < 2; ++iss) {
            int p = iss * 256 + tid;
            int row = p >> 3, c = p & 7, cs = c ^ (row & 7);
            gload_lds16(&Qb[((size_t)(bh << 10) + n0 + row) * 64 + cs * 8],
                        (char*)&Qtile[buf][0] + p * 16);
            gload_lds16(&QT[((size_t)bh * 64 + row) * 1024 + n0 + cs * 8],
                        (char*)&Ttile[buf][0] + p * 16);
        }
    };

    short8v ka[2];
#pragma unroll
    for (int kc = 0; kc < 2; ++kc)
        ka[kc] = *(const short8v*)&Kb[((size_t)(bh << 10) + mw + lr) * 64 + kc * 32 + lg * 8];

    f32x4 dk[4];
#pragma unroll
    for (int qb = 0; qb < 4; ++qb) dk[qb] = (f32x4){0.f, 0.f, 0.f, 0.f};

    stage(0, 0);
    __syncthreads();
    int buf = 0;
    for (int ntl = 0; ntl < 16; ++ntl) {
        const int n0 = ntl * 64;
        float lse_c[4];
#pragma unroll
        for (int ct = 0; ct < 4; ++ct)
            lse_c[ct] = LSE[(size_t)(bh << 10) + n0 + ct * 16 + lr];
        if (ntl < 15) stage(buf ^ 1, n0 + 64);
        const char* Qt = (const char*)&Qtile[buf][0];
        const char* Tt = (const char*)&Ttile[buf][0];
#pragma unroll
        for (int ct = 0; ct < 4; ++ct) {
            int brow = ct * 16 + lr;
            short8v bq0 = *(const short8v*)(Qt + brow * 128 + ((lg) ^ (brow & 7)) * 16);
            short8v bq1 = *(const short8v*)(Qt + brow * 128 + ((lg + 4) ^ (brow & 7)) * 16);
            f32x4 s = {0.f, 0.f, 0.f, 0.f};
            s = __builtin_amdgcn_mfma_f32_16x16x32_bf16(ka[0], bq0, s, 0, 0, 0);
            s = __builtin_amdgcn_mfma_f32_16x16x32_bf16(ka[1], bq1, s, 0, 0, 0);
#pragma unroll
            for (int r = 0; r < 4; ++r) {
                float p = __expf(s[r] * BETA - lse_c[ct]);
                int row = lg * 4 + r;
                int off = (row * 64 + ct * 16 + lr) ^ ((row & 7) << 3);
                Pw[off] = f2b(p);
            }
        }
        short8v pa[2];
#pragma unroll
        for (int kc = 0; kc < 2; ++kc) {
            int off = (lr * 64 + kc * 32 + lg * 8) ^ ((lr & 7) << 3);
            pa[kc] = *(const short8v*)&Pw[off];
        }
#pragma unroll
        for (int qb = 0; qb < 4; ++qb) {
            int brow = qb * 16 + lr;
            short8v b0 = *(const short8v*)(Tt + brow * 128 + ((lg) ^ (brow & 7)) * 16);
            short8v b1 = *(const short8v*)(Tt + brow * 128 + ((lg + 4) ^ (brow & 7)) * 16);
            dk[qb] = __builtin_amdgcn_mfma_f32_16x16x32_bf16(pa[0], b0, dk[qb], 0, 0, 0);
            dk[qb] = __builtin_amdgcn_mfma_f32_16x16x32_bf16(pa[1], b1, dk[qb], 0, 0, 0);
        }
        __syncthreads();
        buf ^= 1;
    }
    const int b = bh >> 4, h = bh & 15;
#pragma unroll
    for (int qb = 0; qb < 4; ++qb)
#pragma unroll
        for (int r = 0; r < 4; ++r)
            DQK[((size_t)(b << 10) + mw + lg * 4 + r) * 2048 + 1024 + h * 64 + qb * 16 + lr] = f2b(-dk[qb][r]);
}

// ---------------- K8: finalize energy ----------------
__global__ __launch_bounds__(256) void k_fin(const float* __restrict__ pl,
                                             const float* __restrict__ ph,
                                             float* __restrict__ out) {
    const int tid = threadIdx.x;
    float s1 = 0.f, s2 = 0.f;
    for (int i = tid; i < 4096; i += 256) s1 += pl[i];
    if (tid < 256) s2 = ph[tid];
#pragma unroll
    for (int off = 32; off; off >>= 1) {
        s1 += __shfl_down(s1, off);
        s2 += __shfl_down(s2, off);
    }
    __shared__ float r1[4], r2[4];
    if ((tid & 63) == 0) { r1[tid >> 6] = s1; r2[tid >> 6] = s2; }
    __syncthreads();
    if (tid == 0) {
        float S1 = r1[0] + r1[1] + r1[2] + r1[3];
        float S2 = r2[0] + r2[1] + r2[2] + r2[3];
        out[(size_t)4194304] = -INV_BETA * S1 - 0.5f * S2;
    }
}

extern "C" void kernel_launch(void* const* d_in, const int* in_sizes, int n_in,
                              void* d_out, int out_size, void* d_ws, size_t ws_size,
                              hipStream_t stream) {
    (void)in_sizes; (void)n_in; (void)out_size; (void)ws_size;
    const float* x    = (const float*)d_in[0];
    const float* Wq   = (const float*)d_in[1];
    const float* Wk   = (const float*)d_in[2];
    const float* Whop = (const float*)d_in[3];
    float* out = (float*)d_out;
    float* ws = (float*)d_ws;

    unsigned short* XB   = (unsigned short*)(ws + OFF_XB);
    unsigned short* WCB  = (unsigned short*)(ws + OFF_WCB);
    unsigned short* WCTB = (unsigned short*)(ws + OFF_WCTB);
    unsigned short* WHB  = (unsigned short*)(ws + OFF_WHB);
    unsigned short* WHTB = (unsigned short*)(ws + OFF_WHTB);
    unsigned short* Hn   = (unsigned short*)(ws + OFF_H);
    unsigned short* Qb   = (unsigned short*)(ws + OFF_QB);
    unsigned short* Kb   = (unsigned short*)(ws + OFF_KB);
    unsigned short* QT   = (unsigned short*)(ws + OFF_QT);
    unsigned short* KT   = (unsigned short*)(ws + OFF_KT);
    unsigned short* DQK  = (unsigned short*)(ws + OFF_DQK);
    float* LSE = ws + OFF_LSE;
    float* PL  = ws + OFF_PL;
    float* PH  = ws + OFF_PH;

    dim3 blk(256);
    k_prep<<<dim3(16384), blk, 0, stream>>>(x, Wq, Wk, Whop, XB, WCB, WHB, WCTB, WHTB);

    mm_proj<<<dim3(1024), blk, 0, stream>>>(XB, WCB, Qb, Kb);
    k_tqk<<<dim3(16, 64, 2), blk, 0, stream>>>(Qb, Kb, QT, KT);
    k_dq<<<dim3(1024), blk, 0, stream>>>(Qb, Kb, KT, LSE, PL, DQK);
    k_dk<<<dim3(1024), blk, 0, stream>>>(Qb, Kb, QT, LSE, DQK);

    mm_hopfwd<<<dim3(256), dim3(512), 0, stream>>>(XB, WHTB, Hn, PH);
    mm_gradall<<<dim3(512), blk, 0, stream>>>(Hn, WHB, DQK, WCTB, out);
    k_fin<<<dim3(1), blk, 0, stream>>>(PL, PH, out);
}